// Round 1
// baseline (14587.514 us; speedup 1.0000x reference)
//
#include <hip/hip_runtime.h>

typedef unsigned short u16;
typedef __attribute__((ext_vector_type(8))) unsigned short ushort8;
typedef __attribute__((ext_vector_type(4))) float f32x4;
typedef __attribute__((ext_vector_type(8))) __bf16 bf16x8;

#define N_B 256
#define LSEQ 128
#define AROW 2304   // 768 (h1) + 2*768 (h2 double-buffer phases)

// ---- workspace layout (byte offsets) ----
#define OFF_BP2   0ull
#define SZ_BP2    (48ull*192*512*2)
#define OFF_BP1   (OFF_BP2 + SZ_BP2)
#define SZ_BP1    (24ull*192*512*2)
#define OFF_W1P   (OFF_BP1 + SZ_BP1)
#define SZ_W1P    (24ull*32*512*2)
#define OFF_WIH1T (OFF_W1P + SZ_W1P)
#define SZ_WIH1T  (9ull*3072*4)
#define OFF_BS1   (OFF_WIH1T + SZ_WIH1T)
#define OFF_BS2   (OFF_BS1 + 3072*4)
#define OFF_ZERO  (OFF_BS2 + 3072*4)
#define OFF_ACAT  OFF_ZERO
#define SZ_ACAT   (256ull*2304*2)
#define OFF_G1P   (OFF_ACAT + SZ_ACAT)
#define SZ_G1P    (256ull*3072*4)
#define OFF_C1    (OFF_G1P + SZ_G1P)
#define OFF_C2    (OFF_C1 + 256ull*768*4)
#define OFF_SB    (OFF_C2 + 256ull*768*4)
#define OFF_END   (OFF_SB + 256*4)
#define ZERO_BYTES (OFF_END - OFF_ZERO)

__device__ __forceinline__ float sigf(float v) { return 1.f / (1.f + __expf(-v)); }
__device__ __forceinline__ float tanhfast(float v) { return 1.f - 2.f / (__expf(2.f * v) + 1.f); }
__device__ __forceinline__ u16 f2bf(float f) {
  union { float f; unsigned u; } v; v.f = f;
  unsigned r = v.u + 0x7fffu + ((v.u >> 16) & 1u);   // round-to-nearest-even
  return (u16)(r >> 16);
}

// ---------------------------------------------------------------------------
// One-time packing: weights -> bf16 MFMA fragment layout.
// B fragment for tile (kt, jt): lane l, elem e holds B[kt*32 + (l>>4)*8 + e][jt*16 + (l&15)].
// Both A and B use k = (l>>4)*8 + e, so the GEMM is layout-safe (slot-paired).
// ---------------------------------------------------------------------------
__global__ void pack_kernel(const float* __restrict__ Wih1, const float* __restrict__ bih1,
                            const float* __restrict__ Whh1, const float* __restrict__ bhh1,
                            const float* __restrict__ Wih2, const float* __restrict__ bih2,
                            const float* __restrict__ Whh2, const float* __restrict__ bhh2,
                            const float* __restrict__ W1,
                            u16* __restrict__ Bp2, u16* __restrict__ Bp1, u16* __restrict__ W1p,
                            float* __restrict__ Wih1t, float* __restrict__ bs1, float* __restrict__ bs2) {
  const long NB2 = 48l * 192 * 512, NB1 = 24l * 192 * 512, NW1 = 24l * 32 * 512, NT = 9l * 3072;
  const long total = NB2 + NB1 + NW1 + NT + 3072 * 2;
  for (long idx = (long)blockIdx.x * 256 + threadIdx.x; idx < total; idx += (long)gridDim.x * 256) {
    if (idx < NB2) {                       // Wcat2 = [W_ih2 ; W_hh2] for gates2 (K=1536)
      long kt = idx / (192 * 512); long r = idx % (192 * 512);
      int jt = (int)(r / 512); int s = (int)(r % 512);
      int l = s >> 3, e = s & 7;
      int k = (int)kt * 32 + ((l >> 4) * 8) + e;
      int j = jt * 16 + (l & 15);
      float v = (k < 768) ? Wih2[j * 768 + k] : Whh2[j * 768 + k - 768];
      Bp2[idx] = f2bf(v);
    } else if (idx < NB2 + NB1) {          // W_hh1 for gates1_partial (K=768)
      long i = idx - NB2;
      long kt = i / (192 * 512); long r = i % (192 * 512);
      int jt = (int)(r / 512); int s = (int)(r % 512);
      int l = s >> 3, e = s & 7;
      int k = (int)kt * 32 + ((l >> 4) * 8) + e;
      int j = jt * 16 + (l & 15);
      Bp1[i] = f2bf(Whh1[j * 768 + k]);
    } else if (idx < NB2 + NB1 + NW1) {    // W1 for FC (K=768, N=512)
      long i = idx - NB2 - NB1;
      long kt = i / (32 * 512); long r = i % (32 * 512);
      int jt = (int)(r / 512); int s = (int)(r % 512);
      int l = s >> 3, e = s & 7;
      int k = (int)kt * 32 + ((l >> 4) * 8) + e;
      int j = jt * 16 + (l & 15);
      W1p[i] = f2bf(W1[j * 768 + k]);
    } else if (idx < NB2 + NB1 + NW1 + NT) {  // W_ih1 transposed (fp32, coalesced reads)
      long i = idx - NB2 - NB1 - NW1;
      int k = (int)(i / 3072), j = (int)(i % 3072);
      Wih1t[i] = Wih1[j * 9 + k];
    } else {
      long i = idx - NB2 - NB1 - NW1 - NT;
      if (i < 3072) bs1[i] = bih1[i] + bhh1[i];
      else { long j = i - 3072; bs2[j] = bih2[j] + bhh2[j]; }
    }
  }
}

// ---------------------------------------------------------------------------
// step_A: blocks 0..191  -> gates2 GEMM (K=1536, quadrant-grouped cols) + h2/c2 update
//         blocks 192..383-> gates1_partial GEMM (K=768), raw fp32 out
// ---------------------------------------------------------------------------
__global__ __launch_bounds__(256) void step_A(
    u16* __restrict__ Acat, const u16* __restrict__ Bp2, const u16* __restrict__ Bp1,
    float* __restrict__ g1p, float* __restrict__ c2, const float* __restrict__ bs2, int t) {
  __shared__ ushort8 sbuf[16 * 64];       // 16 fragments staged per K-chunk (K=64)
  __shared__ float gbuf[4][64][16];       // quadrant exchange for h2 activation
  const int tid = threadIdx.x, l = tid & 63, w = tid >> 6;
  const int bid = blockIdx.x;
  const bool p1 = bid < 192;
  if (!p1 && t == 127) return;            // gates1_partial(128) not needed

  int rowbase, mg = 0, jb = 0, KT;
  const u16* Bp;
  const int rdbase = 768 + (t & 1) * 768;        // h2(t-1) read region
  const int wrbase = 768 + ((t + 1) & 1) * 768;  // h2(t) write region
  if (p1) { mg = bid % 48; rowbase = (bid / 48) * 64; KT = 48; Bp = Bp2; }
  else { int b = bid - 192; jb = b % 48; rowbase = (b / 48) * 64; KT = 24; Bp = Bp1; }

  f32x4 acc[4] = {};
  const int nchunks = KT >> 1;
  for (int kc = 0; kc < nchunks; ++kc) {
    __syncthreads();
#pragma unroll
    for (int i = 0; i < 4; ++i) {         // stage 16 frags (8 A, 8 B) with 256 threads
      int slot = tid + i * 256;
      int f = slot >> 6, lf = slot & 63;
      const u16* gp;
      if (f < 8) {                        // A fragments: 4 row-tiles x 2 k-tiles
        int kt2 = f >> 2, rt = f & 3, kt = kc * 2 + kt2;
        int row = rowbase + rt * 16 + (lf & 15);
        int col = (p1 && kt >= 24) ? (rdbase + (kt - 24) * 32 + ((lf >> 4) * 8))
                                   : (kt * 32 + ((lf >> 4) * 8));
        gp = Acat + row * AROW + col;
      } else {                            // B fragments: 4 j-tiles x 2 k-tiles
        int q = (f - 8) & 3, kt2 = (f - 8) >> 2, kt = kc * 2 + kt2;
        int jt = p1 ? (q * 48 + mg) : (jb * 4 + q);
        gp = Bp + (long)(kt * 192 + jt) * 512 + lf * 8;
      }
      sbuf[slot] = *reinterpret_cast<const ushort8*>(gp);
    }
    __syncthreads();
#pragma unroll
    for (int kt2 = 0; kt2 < 2; ++kt2) {
      ushort8 b = sbuf[(8 + kt2 * 4 + w) * 64 + l];
#pragma unroll
      for (int rt = 0; rt < 4; ++rt) {
        ushort8 a = sbuf[(kt2 * 4 + rt) * 64 + l];
        acc[rt] = __builtin_amdgcn_mfma_f32_16x16x32_bf16(
            __builtin_bit_cast(bf16x8, a), __builtin_bit_cast(bf16x8, b), acc[rt], 0, 0, 0);
      }
    }
  }

  if (p1) {
    // wave w owns quadrant w (cols w*768 + mg*16 + 0..15); exchange via LDS, then activate
#pragma unroll
    for (int rt = 0; rt < 4; ++rt)
#pragma unroll
      for (int reg = 0; reg < 4; ++reg) {
        int rl = rt * 16 + (l >> 4) * 4 + reg;
        gbuf[w][rl][l & 15] = acc[rt][reg] + bs2[w * 768 + mg * 16 + (l & 15)];
      }
    __syncthreads();
    for (int p = tid; p < 1024; p += 256) {
      int r = p >> 4, m = p & 15;
      float gi = gbuf[0][r][m], gf = gbuf[1][r][m], gg = gbuf[2][r][m], go = gbuf[3][r][m];
      int n = rowbase + r, mG = mg * 16 + m;
      float co = c2[n * 768 + mG];
      float cn = sigf(gf) * co + sigf(gi) * tanhfast(gg);
      float h = sigf(go) * tanhfast(cn);
      c2[n * 768 + mG] = cn;
      Acat[n * AROW + wrbase + mG] = f2bf(h);
    }
  } else {
    int col = (jb * 4 + w) * 16 + (l & 15);
#pragma unroll
    for (int rt = 0; rt < 4; ++rt)
#pragma unroll
      for (int reg = 0; reg < 4; ++reg) {
        int row = rowbase + rt * 16 + (l >> 4) * 4 + reg;
        g1p[row * 3072 + col] = acc[rt][reg];   // bias added in step_BC
      }
  }
}

// ---------------------------------------------------------------------------
// step_BC (16 blocks x 16 rows): FC head -> out(t); store integration (fp32);
// h1(t+1) activation (x-part + store-term + bias folded in).  t=-1 bootstraps.
// ---------------------------------------------------------------------------
__global__ __launch_bounds__(256) void step_BC(
    const float* __restrict__ x, u16* __restrict__ Acat, const u16* __restrict__ W1p,
    const float* __restrict__ g1p, float* __restrict__ c1,
    const float* __restrict__ bs1, const float* __restrict__ Wih1t,
    const float* __restrict__ b1, const float* __restrict__ W2, const float* __restrict__ b2,
    float* __restrict__ store_buf, float* __restrict__ outs, float* __restrict__ stores, int t) {
  __shared__ float red[4][16];
  __shared__ float cs_l[16];
  __shared__ float xr[16][8];
  const int tid = threadIdx.x, l = tid & 63, w = tid >> 6;
  const int n0 = blockIdx.x * 16;
  const int h2rd = 768 + ((t + 1) & 1) * 768;   // h2(t) region written by step_A(t)

  if (t >= 0) {
    f32x4 acc[8] = {};
    for (int kt = 0; kt < 24; ++kt) {
      ushort8 a = *reinterpret_cast<const ushort8*>(
          Acat + (n0 + (l & 15)) * AROW + h2rd + kt * 32 + ((l >> 4) * 8));
#pragma unroll
      for (int ct = 0; ct < 8; ++ct) {
        ushort8 b = *reinterpret_cast<const ushort8*>(
            W1p + (long)(kt * 32 + w * 8 + ct) * 512 + l * 8);
        acc[ct] = __builtin_amdgcn_mfma_f32_16x16x32_bf16(
            __builtin_bit_cast(bf16x8, a), __builtin_bit_cast(bf16x8, b), acc[ct], 0, 0, 0);
      }
    }
    float part[4] = {0.f, 0.f, 0.f, 0.f};
#pragma unroll
    for (int ct = 0; ct < 8; ++ct)
#pragma unroll
      for (int reg = 0; reg < 4; ++reg) {
        int col = w * 128 + ct * 16 + (l & 15);
        float v = fmaxf(acc[ct][reg] + b1[col], 0.f);
        part[reg] += v * W2[col];
      }
#pragma unroll
    for (int m = 1; m < 16; m <<= 1)
#pragma unroll
      for (int reg = 0; reg < 4; ++reg) part[reg] += __shfl_xor(part[reg], m);
    if ((l & 15) == 0)
#pragma unroll
      for (int reg = 0; reg < 4; ++reg) red[w][(l >> 4) * 4 + reg] = part[reg];
  }
  __syncthreads();
  if (tid < 16) {
    int n = n0 + tid;
    float ov = 0.f;
    if (t >= 0) {
      ov = red[0][tid] + red[1][tid] + red[2][tid] + red[3][tid] + b2[0];
      outs[n * LSEQ + t] = ov;
    }
    if (t < 127) {
      float cs = store_buf[n] + x[(n * LSEQ + t + 1) * 8] - ov;   // exact fp32 integration
      store_buf[n] = cs;
      stores[n * LSEQ + t + 1] = cs;
      cs_l[tid] = cs;
    }
  }
  if (t < 127 && tid < 128) {
    int r = tid >> 3, k = tid & 7;
    xr[r][k] = x[((n0 + r) * LSEQ + t + 1) * 8 + k];
  }
  __syncthreads();
  if (t < 127) {
    for (int p = tid; p < 16 * 768; p += 256) {
      int r = p / 768, m = p - r * 768;
      int n = n0 + r;
      float g[4];
#pragma unroll
      for (int q = 0; q < 4; ++q) {
        int j = m + q * 768;
        float a = g1p[n * 3072 + j] + bs1[j] + cs_l[r] * Wih1t[8 * 3072 + j];
#pragma unroll
        for (int k = 0; k < 8; ++k) a += xr[r][k] * Wih1t[k * 3072 + j];
        g[q] = a;
      }
      float co = c1[n * 768 + m];
      float cn = sigf(g[1]) * co + sigf(g[0]) * tanhfast(g[2]);
      float h = sigf(g[3]) * tanhfast(cn);
      c1[n * 768 + m] = cn;
      Acat[n * AROW + m] = f2bf(h);
    }
  }
}

extern "C" void kernel_launch(void* const* d_in, const int* in_sizes, int n_in,
                              void* d_out, int out_size, void* d_ws, size_t ws_size,
                              hipStream_t stream) {
  const float* x    = (const float*)d_in[0];
  const float* Wih1 = (const float*)d_in[1];
  const float* bih1 = (const float*)d_in[2];
  const float* Whh1 = (const float*)d_in[3];
  const float* bhh1 = (const float*)d_in[4];
  const float* Wih2 = (const float*)d_in[5];
  const float* bih2 = (const float*)d_in[6];
  const float* Whh2 = (const float*)d_in[7];
  const float* bhh2 = (const float*)d_in[8];
  const float* W1   = (const float*)d_in[9];
  const float* b1   = (const float*)d_in[10];
  const float* W2   = (const float*)d_in[11];
  const float* b2   = (const float*)d_in[12];

  char* ws = (char*)d_ws;
  u16* Bp2 = (u16*)(ws + OFF_BP2);
  u16* Bp1 = (u16*)(ws + OFF_BP1);
  u16* W1p = (u16*)(ws + OFF_W1P);
  float* Wih1t = (float*)(ws + OFF_WIH1T);
  float* bs1 = (float*)(ws + OFF_BS1);
  float* bs2 = (float*)(ws + OFF_BS2);
  u16* Acat = (u16*)(ws + OFF_ACAT);
  float* g1p = (float*)(ws + OFF_G1P);
  float* c1 = (float*)(ws + OFF_C1);
  float* c2 = (float*)(ws + OFF_C2);
  float* sb = (float*)(ws + OFF_SB);
  float* outs = (float*)d_out;
  float* stores = outs + N_B * LSEQ;

  pack_kernel<<<2048, 256, 0, stream>>>(Wih1, bih1, Whh1, bhh1, Wih2, bih2, Whh2, bhh2, W1,
                                        Bp2, Bp1, W1p, Wih1t, bs1, bs2);
  hipMemsetAsync(ws + OFF_ZERO, 0, ZERO_BYTES, stream);

  // bootstrap: h1(0), c1(0), cur_store(0), stores[:,0]  (g1p/c/stores zeroed above)
  step_BC<<<16, 256, 0, stream>>>(x, Acat, W1p, g1p, c1, bs1, Wih1t, b1, W2, b2, sb, outs, stores, -1);
  for (int t = 0; t < 128; ++t) {
    step_A<<<384, 256, 0, stream>>>(Acat, Bp2, Bp1, g1p, c2, bs2, t);
    step_BC<<<16, 256, 0, stream>>>(x, Acat, W1p, g1p, c1, bs1, Wih1t, b1, W2, b2, sb, outs, stores, t);
  }
}